// Round 1
// baseline (16024.213 us; speedup 1.0000x reference)
//
#include <hip/hip_runtime.h>
#include <math.h>

#define NB 2
#define NS 2048
#define NTOK (NB*NS)
#define DM 2048
#define NHQ 16
#define NHKV 8
#define HD 128
#define NE 8
#define NF 4096
#define RMS_EPS 1e-6f

#define BM 128
#define BN 128
#define BK 8

enum { GM_PLAIN=0, GM_RESID=1, GM_WI0=2, GM_WI1=3, GM_WOE=4 };

// ---------------- RMSNorm: one block per row, D=2048 ----------------
__global__ __launch_bounds__(256)
void rmsnorm_k(const float* __restrict__ x, const float* __restrict__ sc,
               float* __restrict__ o)
{
    int row = blockIdx.x;
    int t = threadIdx.x;
    const float4* xr = reinterpret_cast<const float4*>(x + (size_t)row * DM);
    float4 a = xr[t];
    float4 b = xr[t + 256];
    float ss = a.x*a.x + a.y*a.y + a.z*a.z + a.w*a.w
             + b.x*b.x + b.y*b.y + b.z*b.z + b.w*b.w;
#pragma unroll
    for (int off = 32; off > 0; off >>= 1) ss += __shfl_xor(ss, off, 64);
    __shared__ float red[4];
    if ((t & 63) == 0) red[t >> 6] = ss;
    __syncthreads();
    float rstd = rsqrtf((red[0]+red[1]+red[2]+red[3]) * (1.0f / DM) + RMS_EPS);
    const float4* sv = reinterpret_cast<const float4*>(sc);
    float4 s0 = sv[t];
    float4 s1 = sv[t + 256];
    float4* orow = reinterpret_cast<float4*>(o + (size_t)row * DM);
    float4 r0, r1;
    r0.x = a.x*rstd*s0.x; r0.y = a.y*rstd*s0.y; r0.z = a.z*rstd*s0.z; r0.w = a.w*rstd*s0.w;
    r1.x = b.x*rstd*s1.x; r1.y = b.y*rstd*s1.y; r1.z = b.z*rstd*s1.z; r1.w = b.w*rstd*s1.w;
    orow[t] = r0; orow[t+256] = r1;
}

// ---------------- Generic fp32 SGEMM, 128x128 tile, BK=8, 256 threads ----------------
// MODE: PLAIN C=A*B | RESID C=A*B+R | WI0 gathered-A -> act | WI1 gathered-A, act=silu(act)*acc
//       WOE A=act rows, scatter w*acc -> mlp0/mlp1 by slot
template<int MODE>
__global__ __launch_bounds__(256)
void sgemm_k(const float* __restrict__ A, const float* __restrict__ B,
             float* __restrict__ C, int M, int N, int K,
             const float* __restrict__ R,
             const int* __restrict__ counts,
             const int* __restrict__ toklist,
             const float* __restrict__ wgts,
             const int* __restrict__ slots,
             float* __restrict__ mlp0, float* __restrict__ mlp1)
{
    constexpr bool MOE = (MODE >= GM_WI0);
    if constexpr (MOE) {
        int e = blockIdx.z;
        M = counts[e];
        if ((int)(blockIdx.x * BM) >= M) return;
        B += (size_t)e * K * N;
        toklist += e * NTOK;
        wgts += e * NTOK;
        slots += e * NTOK;
    }
    int t = threadIdx.x;
    int tx = t & 15, ty = t >> 4;

    __shared__ float As[BK][BM+4];
    __shared__ float Bs[BK][BN+4];

    int arow = t >> 1;
    int acol = (t & 1) * 4;
    int garow = blockIdx.x * BM + arow;
    const float* Arow;
    if constexpr (MODE == GM_WI0 || MODE == GM_WI1) {
        int gi = min(garow, M - 1);
        Arow = A + (size_t)toklist[gi] * K;
    } else if constexpr (MODE == GM_WOE) {
        int gi = min(garow, M - 1);
        Arow = A + (size_t)(toklist[gi] * 2 + slots[gi]) * K;
    } else {
        Arow = A + (size_t)garow * K;
    }
    int brow = t >> 5;
    int bcol = (t & 31) * 4;
    const float* Bp = B + (size_t)brow * N + (size_t)blockIdx.y * BN + bcol;

    float acc[2][2][4][4];
#pragma unroll
    for (int im=0; im<2; ++im)
#pragma unroll
    for (int in=0; in<2; ++in)
#pragma unroll
    for (int i=0; i<4; ++i)
#pragma unroll
    for (int j=0; j<4; ++j) acc[im][in][i][j] = 0.0f;

    float4 av = *reinterpret_cast<const float4*>(Arow + acol);
    float4 bv = *reinterpret_cast<const float4*>(Bp);

    for (int k0 = 0; k0 < K; k0 += BK) {
        __syncthreads();
        As[acol+0][arow] = av.x;
        As[acol+1][arow] = av.y;
        As[acol+2][arow] = av.z;
        As[acol+3][arow] = av.w;
        *reinterpret_cast<float4*>(&Bs[brow][bcol]) = bv;
        __syncthreads();
        if (k0 + BK < K) {
            av = *reinterpret_cast<const float4*>(Arow + k0 + BK + acol);
            bv = *reinterpret_cast<const float4*>(Bp + (size_t)(k0 + BK) * N);
        }
#pragma unroll
        for (int kk = 0; kk < BK; ++kk) {
            float4 a0 = *reinterpret_cast<const float4*>(&As[kk][ty*4]);
            float4 a1 = *reinterpret_cast<const float4*>(&As[kk][64 + ty*4]);
            float4 b0 = *reinterpret_cast<const float4*>(&Bs[kk][tx*4]);
            float4 b1 = *reinterpret_cast<const float4*>(&Bs[kk][64 + tx*4]);
            float af[2][4] = {{a0.x,a0.y,a0.z,a0.w},{a1.x,a1.y,a1.z,a1.w}};
            float bf[2][4] = {{b0.x,b0.y,b0.z,b0.w},{b1.x,b1.y,b1.z,b1.w}};
#pragma unroll
            for (int im=0; im<2; ++im)
#pragma unroll
            for (int i=0; i<4; ++i)
#pragma unroll
            for (int in=0; in<2; ++in)
#pragma unroll
            for (int j=0; j<4; ++j)
                acc[im][in][i][j] = fmaf(af[im][i], bf[in][j], acc[im][in][i][j]);
        }
    }

#pragma unroll
    for (int im=0; im<2; ++im) {
#pragma unroll
        for (int i=0; i<4; ++i) {
            int r = blockIdx.x*BM + im*64 + ty*4 + i;
            if constexpr (MOE) { if (r >= M) continue; }
#pragma unroll
            for (int in=0; in<2; ++in) {
                size_t col = (size_t)blockIdx.y*BN + in*64 + tx*4;
                float4 val;
                val.x = acc[im][in][i][0]; val.y = acc[im][in][i][1];
                val.z = acc[im][in][i][2]; val.w = acc[im][in][i][3];
                if constexpr (MODE == GM_PLAIN) {
                    *reinterpret_cast<float4*>(&C[(size_t)r*N + col]) = val;
                } else if constexpr (MODE == GM_RESID) {
                    float4 rv = *reinterpret_cast<const float4*>(&R[(size_t)r*N + col]);
                    val.x += rv.x; val.y += rv.y; val.z += rv.z; val.w += rv.w;
                    *reinterpret_cast<float4*>(&C[(size_t)r*N + col]) = val;
                } else if constexpr (MODE == GM_WI0) {
                    size_t pr = (size_t)(toklist[r]*2 + slots[r]);
                    *reinterpret_cast<float4*>(&C[pr*N + col]) = val;
                } else if constexpr (MODE == GM_WI1) {
                    size_t pr = (size_t)(toklist[r]*2 + slots[r]);
                    float* cp = &C[pr*N + col];
                    float4 c0 = *reinterpret_cast<const float4*>(cp);
                    val.x *= c0.x / (1.0f + expf(-c0.x));
                    val.y *= c0.y / (1.0f + expf(-c0.y));
                    val.z *= c0.z / (1.0f + expf(-c0.z));
                    val.w *= c0.w / (1.0f + expf(-c0.w));
                    *reinterpret_cast<float4*>(cp) = val;
                } else { // GM_WOE
                    int tok = toklist[r];
                    float w = wgts[r];
                    float* dst = (slots[r] ? mlp1 : mlp0) + (size_t)tok*N + col;
                    val.x *= w; val.y *= w; val.z *= w; val.w *= w;
                    *reinterpret_cast<float4*>(dst) = val;
                }
            }
        }
    }
}

// ---------------- RoPE (in-place on q,k), q also scaled by HD^-0.5 ----------------
__global__ __launch_bounds__(256)
void rope_k(float* __restrict__ qb, float* __restrict__ kb, const int* __restrict__ pos)
{
    int idx = blockIdx.x * 256 + threadIdx.x;   // total = NTOK*(NHQ+NHKV)*64
    int i = idx & 63;
    int h = (idx >> 6) % (NHQ + NHKV);
    int bs = idx / (64 * (NHQ + NHKV));
    float p = (float)pos[bs];
    float freq = 1.0f / powf(10000.0f, (float)i * (1.0f/64.0f));
    float ang = p * freq;
    float sn, cs;
    sincosf(ang, &sn, &cs);
    float* base;
    float scale;
    if (h < NHQ) { base = qb + (size_t)bs*DM + h*HD; scale = 0.08838834764831845f; }
    else         { base = kb + (size_t)bs*(NHKV*HD) + (h-NHQ)*HD; scale = 1.0f; }
    float x1 = base[i], x2 = base[i+64];
    base[i]    = (x1*cs - x2*sn) * scale;
    base[i+64] = (x2*cs + x1*sn) * scale;
}

// ---------------- Flash attention, QT=64, KT=32, 256 threads ----------------
__global__ __launch_bounds__(256)
void attn_k(const float* __restrict__ q, const float* __restrict__ k,
            const float* __restrict__ v, const int* __restrict__ seg,
            float* __restrict__ ctx)
{
    int qt = blockIdx.x, hq = blockIdx.y, b = blockIdx.z;
    int kvh = hq >> 1;
    int q0 = qt * 64;
    int t = threadIdx.x;
    int tx = t & 15, ty = t >> 4;

    __shared__ float Qs[64][HD+4];
    __shared__ float Ks[32][HD+4];
    __shared__ float Vs[32][HD+4];
    __shared__ float Ps[32][68];
    __shared__ int sk[32];

    const float* qbase = q + ((size_t)(b*NS) + q0) * DM + hq*HD;
#pragma unroll
    for (int it = 0; it < 8; ++it) {
        int idx = t + it*256;
        int r = idx >> 5, dq = (idx & 31) * 4;
        *reinterpret_cast<float4*>(&Qs[r][dq]) =
            *reinterpret_cast<const float4*>(qbase + (size_t)r*DM + dq);
    }
    int sq[4];
#pragma unroll
    for (int i=0;i<4;i++) sq[i] = seg[b*NS + q0 + ty*4 + i];

    float m[4] = {-INFINITY,-INFINITY,-INFINITY,-INFINITY};
    float l[4] = {0.f,0.f,0.f,0.f};
    float o[4][8];
#pragma unroll
    for (int i=0;i<4;i++)
#pragma unroll
    for (int j=0;j<8;j++) o[i][j] = 0.f;

    const float* kb = k + (size_t)(b*NS)*(NHKV*HD) + kvh*HD;
    const float* vb = v + (size_t)(b*NS)*(NHKV*HD) + kvh*HD;
    int nkt = 2*qt + 2;
    for (int kt = 0; kt < nkt; ++kt) {
        int k0 = kt * 32;
        __syncthreads();
#pragma unroll
        for (int it = 0; it < 4; ++it) {
            int idx = t + it*256;
            int c = idx >> 5, dq = (idx & 31)*4;
            *reinterpret_cast<float4*>(&Ks[c][dq]) =
                *reinterpret_cast<const float4*>(kb + (size_t)(k0+c)*(NHKV*HD) + dq);
            *reinterpret_cast<float4*>(&Vs[c][dq]) =
                *reinterpret_cast<const float4*>(vb + (size_t)(k0+c)*(NHKV*HD) + dq);
        }
        if (t < 32) sk[t] = seg[b*NS + k0 + t];
        __syncthreads();

        float s[4][2] = {{0,0},{0,0},{0,0},{0,0}};
#pragma unroll 8
        for (int kc = 0; kc < 32; ++kc) {
            float4 kf0 = *reinterpret_cast<const float4*>(&Ks[tx*2+0][kc*4]);
            float4 kf1 = *reinterpret_cast<const float4*>(&Ks[tx*2+1][kc*4]);
#pragma unroll
            for (int i=0;i<4;i++) {
                float4 qf = *reinterpret_cast<const float4*>(&Qs[ty*4+i][kc*4]);
                s[i][0] += qf.x*kf0.x + qf.y*kf0.y + qf.z*kf0.z + qf.w*kf0.w;
                s[i][1] += qf.x*kf1.x + qf.y*kf1.y + qf.z*kf1.z + qf.w*kf1.w;
            }
        }
#pragma unroll
        for (int i=0;i<4;i++) {
            int qpos = q0 + ty*4 + i;
#pragma unroll
            for (int j=0;j<2;j++) {
                int kpos = k0 + tx*2 + j;
                if (kpos > qpos || sk[tx*2+j] != sq[i]) s[i][j] = -1e9f;
            }
        }
        float p[4][2];
#pragma unroll
        for (int i=0;i<4;i++) {
            float x = fmaxf(s[i][0], s[i][1]);
#pragma unroll
            for (int off=1; off<16; off<<=1) x = fmaxf(x, __shfl_xor(x, off, 64));
            float mn = fmaxf(m[i], x);
            float f = expf(m[i] - mn);
            p[i][0] = expf(s[i][0] - mn);
            p[i][1] = expf(s[i][1] - mn);
            float su = p[i][0] + p[i][1];
#pragma unroll
            for (int off=1; off<16; off<<=1) su += __shfl_xor(su, off, 64);
            l[i] = l[i]*f + su;
            m[i] = mn;
#pragma unroll
            for (int jj=0;jj<8;jj++) o[i][jj] *= f;
        }
#pragma unroll
        for (int i=0;i<4;i++) {
            Ps[tx*2+0][ty*4+i] = p[i][0];
            Ps[tx*2+1][ty*4+i] = p[i][1];
        }
        __syncthreads();
#pragma unroll 4
        for (int c=0;c<32;++c) {
            float4 pf = *reinterpret_cast<const float4*>(&Ps[c][ty*4]);
            float pr[4] = {pf.x, pf.y, pf.z, pf.w};
            float4 v0 = *reinterpret_cast<const float4*>(&Vs[c][tx*4]);
            float4 v1 = *reinterpret_cast<const float4*>(&Vs[c][64+tx*4]);
#pragma unroll
            for (int i=0;i<4;i++) {
                o[i][0] = fmaf(pr[i], v0.x, o[i][0]);
                o[i][1] = fmaf(pr[i], v0.y, o[i][1]);
                o[i][2] = fmaf(pr[i], v0.z, o[i][2]);
                o[i][3] = fmaf(pr[i], v0.w, o[i][3]);
                o[i][4] = fmaf(pr[i], v1.x, o[i][4]);
                o[i][5] = fmaf(pr[i], v1.y, o[i][5]);
                o[i][6] = fmaf(pr[i], v1.z, o[i][6]);
                o[i][7] = fmaf(pr[i], v1.w, o[i][7]);
            }
        }
    }
#pragma unroll
    for (int i=0;i<4;i++) {
        float inv = 1.0f / l[i];
        float4 r0, r1;
        r0.x=o[i][0]*inv; r0.y=o[i][1]*inv; r0.z=o[i][2]*inv; r0.w=o[i][3]*inv;
        r1.x=o[i][4]*inv; r1.y=o[i][5]*inv; r1.z=o[i][6]*inv; r1.w=o[i][7]*inv;
        float* cbase = ctx + ((size_t)(b*NS) + q0 + ty*4 + i)*DM + hq*HD;
        *reinterpret_cast<float4*>(cbase + tx*4) = r0;
        *reinterpret_cast<float4*>(cbase + 64 + tx*4) = r1;
    }
}

// ---------------- Gate: logits, top-2, softmax, scatter to expert lists ----------------
__global__ __launch_bounds__(256)
void gate_k(const float* __restrict__ h, const float* __restrict__ gw,
            int* __restrict__ counts, int* __restrict__ toklist,
            float* __restrict__ wgts, int* __restrict__ slots)
{
    int lane = threadIdx.x & 63;
    int tok = blockIdx.x*4 + (threadIdx.x >> 6);
    const float* hr = h + (size_t)tok * DM;
    float acc[8] = {0,0,0,0,0,0,0,0};
    for (int it = 0; it < 32; ++it) {
        int d = lane + it*64;
        float hv = hr[d];
        float4 g0 = *reinterpret_cast<const float4*>(gw + (size_t)d*8);
        float4 g1 = *reinterpret_cast<const float4*>(gw + (size_t)d*8 + 4);
        acc[0] = fmaf(hv, g0.x, acc[0]); acc[1] = fmaf(hv, g0.y, acc[1]);
        acc[2] = fmaf(hv, g0.z, acc[2]); acc[3] = fmaf(hv, g0.w, acc[3]);
        acc[4] = fmaf(hv, g1.x, acc[4]); acc[5] = fmaf(hv, g1.y, acc[5]);
        acc[6] = fmaf(hv, g1.z, acc[6]); acc[7] = fmaf(hv, g1.w, acc[7]);
    }
#pragma unroll
    for (int e=0;e<8;e++)
#pragma unroll
        for (int off=32; off>0; off>>=1) acc[e] += __shfl_xor(acc[e], off, 64);
    if (lane == 0) {
        float v0 = -INFINITY, v1 = -INFINITY; int i0 = 0, i1 = 0;
#pragma unroll
        for (int e=0;e<8;e++) {
            float vv = acc[e];
            if (vv > v0) { v1 = v0; i1 = i0; v0 = vv; i0 = e; }
            else if (vv > v1) { v1 = vv; i1 = e; }
        }
        float e1 = expf(v1 - v0);
        float inv = 1.0f / (1.0f + e1);
        float w0 = inv, w1 = e1 * inv;
        int p0 = atomicAdd(&counts[i0], 1);
        toklist[i0*NTOK + p0] = tok; wgts[i0*NTOK + p0] = w0; slots[i0*NTOK + p0] = 0;
        int p1 = atomicAdd(&counts[i1], 1);
        toklist[i1*NTOK + p1] = tok; wgts[i1*NTOK + p1] = w1; slots[i1*NTOK + p1] = 1;
    }
}

// ---------------- out = intermediate + mlp0 + mlp1 ----------------
__global__ __launch_bounds__(256)
void addmlp_k(const float* __restrict__ inter, const float* __restrict__ m0,
              const float* __restrict__ m1, float* __restrict__ out)
{
    size_t i = (size_t)blockIdx.x*256 + threadIdx.x;
    float4 a = reinterpret_cast<const float4*>(inter)[i];
    float4 b = reinterpret_cast<const float4*>(m0)[i];
    float4 c = reinterpret_cast<const float4*>(m1)[i];
    float4 r;
    r.x = a.x + b.x + c.x; r.y = a.y + b.y + c.y;
    r.z = a.z + b.z + c.z; r.w = a.w + b.w + c.w;
    reinterpret_cast<float4*>(out)[i] = r;
}

extern "C" void kernel_launch(void* const* d_in, const int* in_sizes, int n_in,
                              void* d_out, int out_size, void* d_ws, size_t ws_size,
                              hipStream_t stream)
{
    const float* inputs  = (const float*)d_in[0];
    const float* pre_sc  = (const float*)d_in[1];
    const float* post_sc = (const float*)d_in[2];
    const float* wq      = (const float*)d_in[3];
    const float* wk      = (const float*)d_in[4];
    const float* wv      = (const float*)d_in[5];
    const float* wo      = (const float*)d_in[6];
    const float* gw      = (const float*)d_in[7];
    const float* wi0     = (const float*)d_in[8];
    const float* wi1     = (const float*)d_in[9];
    const float* womlp   = (const float*)d_in[10];
    const int* segids    = (const int*)d_in[11];
    const int* posids    = (const int*)d_in[12];
    float* out = (float*)d_out;

    float* ws = (float*)d_ws;
    const size_t TD = (size_t)NTOK * DM;   // 8388608
    float* lnx   = ws;                     // [0, TD)
    float* ctx   = ws;                     // alias lnx (lnx dead before attention)
    float* qb    = ws + TD;                // TD
    float* kb    = ws + 2*TD;              // TD/2
    float* vb    = ws + 2*TD + TD/2;       // TD/2
    float* inter = ws + 3*TD;              // TD
    float* hbuf  = ws + 4*TD;              // TD
    float* mlp0  = ws + 5*TD;              // TD
    float* mlp1  = ws + 6*TD;              // TD
    float* act   = ws + 7*TD;              // 2*NTOK*NF = 4*TD  -> ends at 11*TD
    int*   counts  = (int*)(ws + 11*TD);
    int*   toklist = counts + NE;
    int*   slots   = toklist + NE*NTOK;
    float* wgtsp   = (float*)(slots + NE*NTOK);

    // 1. pre-attention RMSNorm
    rmsnorm_k<<<NTOK, 256, 0, stream>>>(inputs, pre_sc, lnx);

    // 2. QKV projections
    {
        dim3 gq(NTOK/BM, DM/BN);
        sgemm_k<GM_PLAIN><<<gq, 256, 0, stream>>>(lnx, wq, qb, NTOK, DM, DM,
            nullptr, nullptr, nullptr, nullptr, nullptr, nullptr, nullptr);
        dim3 gk(NTOK/BM, (NHKV*HD)/BN);
        sgemm_k<GM_PLAIN><<<gk, 256, 0, stream>>>(lnx, wk, kb, NTOK, NHKV*HD, DM,
            nullptr, nullptr, nullptr, nullptr, nullptr, nullptr, nullptr);
        sgemm_k<GM_PLAIN><<<gk, 256, 0, stream>>>(lnx, wv, vb, NTOK, NHKV*HD, DM,
            nullptr, nullptr, nullptr, nullptr, nullptr, nullptr, nullptr);
    }

    // 3. RoPE (+ q scale)
    rope_k<<<(NTOK*(NHQ+NHKV)*64)/256, 256, 0, stream>>>(qb, kb, posids);

    // 4. causal GQA flash attention
    attn_k<<<dim3(NS/64, NHQ, NB), 256, 0, stream>>>(qb, kb, vb, segids, ctx);

    // 5. output projection + residual
    sgemm_k<GM_RESID><<<dim3(NTOK/BM, DM/BN), 256, 0, stream>>>(ctx, wo, inter,
        NTOK, DM, DM, inputs, nullptr, nullptr, nullptr, nullptr, nullptr, nullptr);

    // 6. post-attention RMSNorm
    rmsnorm_k<<<NTOK, 256, 0, stream>>>(inter, post_sc, hbuf);

    // 7. gating: top-2 routing
    hipMemsetAsync(counts, 0, NE*sizeof(int), stream);
    gate_k<<<NTOK/4, 256, 0, stream>>>(hbuf, gw, counts, toklist, wgtsp, slots);

    // 8. MoE: act = silu(h@wi0)*(h@wi1), gathered per expert
    sgemm_k<GM_WI0><<<dim3(NTOK/BM, NF/BN, NE), 256, 0, stream>>>(hbuf, wi0, act,
        0, NF, DM, nullptr, counts, toklist, wgtsp, slots, nullptr, nullptr);
    sgemm_k<GM_WI1><<<dim3(NTOK/BM, NF/BN, NE), 256, 0, stream>>>(hbuf, wi1, act,
        0, NF, DM, nullptr, counts, toklist, wgtsp, slots, nullptr, nullptr);

    // 9. MoE down-proj, weighted scatter to slot buffers (race-free)
    sgemm_k<GM_WOE><<<dim3(NTOK/BM, DM/BN, NE), 256, 0, stream>>>(act, womlp, nullptr,
        0, DM, NF, nullptr, counts, toklist, wgtsp, slots, mlp0, mlp1);

    // 10. final residual sum
    addmlp_k<<<(unsigned)(TD/4/256), 256, 0, stream>>>(inter, mlp0, mlp1, out);
}